// Round 17
// baseline (565.057 us; speedup 1.0000x reference)
//
#include <hip/hip_runtime.h>
#include <hip/hip_bf16.h>
#include <math.h>

// ---------- helpers ----------
typedef __bf16 bf16x8 __attribute__((ext_vector_type(8)));
typedef float  f32x4  __attribute__((ext_vector_type(4)));
typedef unsigned short u16x8 __attribute__((ext_vector_type(8)));
typedef unsigned short u16x4 __attribute__((ext_vector_type(4)));

#define DEV static __device__ __forceinline__

DEV void gload16(const void* g, void* l) {
  __builtin_amdgcn_global_load_lds((__attribute__((address_space(1))) void*)g,
                                   (__attribute__((address_space(3))) void*)l,
                                   16, 0, 0);
}

DEV float bf2f(unsigned short u) {
  unsigned v = ((unsigned)u) << 16;
  return __builtin_bit_cast(float, v);
}
DEV unsigned short f2bf(float f) {
  unsigned u = __builtin_bit_cast(unsigned, f);
  u = u + 0x7fffu + ((u >> 16) & 1u);   // round-to-nearest-even
  return (unsigned short)(u >> 16);
}

// ---------- rmsnorm: fp32 [S,H] -> bf16 [S,H] ----------
__global__ __launch_bounds__(256) void rmsnorm_k(const float* __restrict__ x,
    const float* __restrict__ w, unsigned short* __restrict__ out, int H) {
  int row = blockIdx.x;
  const float4* xr = (const float4*)(x + (size_t)row * H);
  float4 a = xr[threadIdx.x * 2], b = xr[threadIdx.x * 2 + 1];
  float ss = a.x*a.x + a.y*a.y + a.z*a.z + a.w*a.w
           + b.x*b.x + b.y*b.y + b.z*b.z + b.w*b.w;
#pragma unroll
  for (int o = 32; o; o >>= 1) ss += __shfl_down(ss, o, 64);
  __shared__ float red[4];
  if ((threadIdx.x & 63) == 0) red[threadIdx.x >> 6] = ss;
  __syncthreads();
  float rs = rsqrtf((red[0] + red[1] + red[2] + red[3]) * (1.0f / 2048.0f) + 1e-5f);
  size_t base = (size_t)row * H + threadIdx.x * 8;
  const float* wv = w + threadIdx.x * 8;
  float vals[8] = {a.x, a.y, a.z, a.w, b.x, b.y, b.z, b.w};
  u16x8 o8;
#pragma unroll
  for (int i = 0; i < 8; ++i) o8[i] = f2bf(vals[i] * rs * wv[i]);
  *(u16x8*)(out + base) = o8;
}

// ---------- split-K reduce + residual + rmsnorm (wo path) ----------
__global__ __launch_bounds__(256) void reduce4rms_k(const float* __restrict__ part,
    const float* __restrict__ resid, const float* __restrict__ w,
    float* __restrict__ x2, unsigned short* __restrict__ nxo, int H, size_t mn) {
  const int row = blockIdx.x, t = threadIdx.x;
  size_t base = (size_t)row * H + t * 8;
  float v[8];
  {
    float4 a = ((const float4*)(resid + base))[0];
    float4 b = ((const float4*)(resid + base))[1];
    v[0]=a.x; v[1]=a.y; v[2]=a.z; v[3]=a.w; v[4]=b.x; v[5]=b.y; v[6]=b.z; v[7]=b.w;
  }
#pragma unroll
  for (int s = 0; s < 4; ++s) {
    const float4* p4 = (const float4*)(part + (size_t)s * mn + base);
    float4 pa = p4[0], pb = p4[1];
    v[0]+=pa.x; v[1]+=pa.y; v[2]+=pa.z; v[3]+=pa.w;
    v[4]+=pb.x; v[5]+=pb.y; v[6]+=pb.z; v[7]+=pb.w;
  }
  float ss = 0.f;
#pragma unroll
  for (int i = 0; i < 8; ++i) ss += v[i] * v[i];
  float4 o0 = {v[0],v[1],v[2],v[3]}, o1 = {v[4],v[5],v[6],v[7]};
  ((float4*)(x2 + base))[0] = o0;
  ((float4*)(x2 + base))[1] = o1;
#pragma unroll
  for (int o = 32; o; o >>= 1) ss += __shfl_down(ss, o, 64);
  __shared__ float red[4];
  if ((t & 63) == 0) red[t >> 6] = ss;
  __syncthreads();
  float rs = rsqrtf((red[0] + red[1] + red[2] + red[3]) * (1.0f / 2048.0f) + 1e-5f);
  const float* wv = w + t * 8;
  u16x8 o8;
#pragma unroll
  for (int i = 0; i < 8; ++i) o8[i] = f2bf(v[i] * rs * wv[i]);
  *(u16x8*)(nxo + base) = o8;
}

// ---------- transpose+convert core: 64x64 tile ----------
DEV void wtrans_body(const float* __restrict__ W, unsigned short* __restrict__ Wt,
                     int R, int C, int ilv, int bx, int by, int t,
                     unsigned short (*tile)[68]) {
  const int c0 = bx * 64, r0 = by * 64;
  const int lr = t >> 4, lc4 = (t & 15) * 4;
#pragma unroll
  for (int i = 0; i < 4; ++i) {
    float4 v = *(const float4*)&W[(size_t)(r0 + lr + i * 16) * C + c0 + lc4];
    u16x4 s4;
    s4[0] = f2bf(v.x); s4[1] = f2bf(v.y); s4[2] = f2bf(v.z); s4[3] = f2bf(v.w);
    *(u16x4*)&tile[lr + i * 16][lc4] = s4;
  }
  __syncthreads();
  const int oc = t >> 3, seg = (t & 7) * 8;
#pragma unroll
  for (int i = 0; i < 2; ++i) {
    int c = c0 + oc + i * 32;
    u16x8 o8;
#pragma unroll
    for (int j = 0; j < 8; ++j) o8[j] = tile[seg + j][oc + i * 32];
    size_t dstrow = (ilv < 0) ? (size_t)c
                              : (size_t)(c >> 4) * 32 + (c & 15) + ilv * 16;
    *(u16x8*)&Wt[dstrow * R + r0 + seg] = o8;
  }
}

__global__ __launch_bounds__(256) void wtrans64_k(const float* __restrict__ W,
    unsigned short* __restrict__ Wt, int R, int C, int ilv) {
  __shared__ unsigned short tile[64][68];
  wtrans_body(W, Wt, R, C, ilv, blockIdx.x, blockIdx.y, threadIdx.x, tile);
}

__global__ __launch_bounds__(256) void wtrans4_k(
    const float* __restrict__ s0, const float* __restrict__ s1,
    const float* __restrict__ s2, const float* __restrict__ s3,
    unsigned short* __restrict__ d0, unsigned short* __restrict__ d1,
    unsigned short* __restrict__ d2, unsigned short* __restrict__ d3,
    int R, int C) {
  __shared__ unsigned short tile[64][68];
  const float* s = (blockIdx.z == 0) ? s0 : (blockIdx.z == 1) ? s1
                 : (blockIdx.z == 2) ? s2 : s3;
  unsigned short* d = (blockIdx.z == 0) ? d0 : (blockIdx.z == 1) ? d1
                    : (blockIdx.z == 2) ? d2 : d3;
  wtrans_body(s, d, R, C, -1, blockIdx.x, blockIdx.y, threadIdx.x, tile);
}

__global__ __launch_bounds__(256) void wtrans13_k(
    const float* __restrict__ w1, const float* __restrict__ w3,
    unsigned short* __restrict__ dst, int R, int C) {
  __shared__ unsigned short tile[64][68];
  const float* s = blockIdx.z ? w3 : w1;
  wtrans_body(s, dst, R, C, (int)blockIdx.z, blockIdx.x, blockIdx.y,
              threadIdx.x, tile);
}

// ============ 256x256 GEMM, 16x16x32 MFMA, 2-phase fragment-reuse ============
#define STG_A(H, BUF, KC) do {                                                 \
    gload16(Asrc0 + (size_t)(H) * 128 * lda + (KC),                            \
            &lds[(BUF) * 16384 + (H) * 8192 + w * 1024]);                      \
    gload16(Asrc1 + (size_t)(H) * 128 * lda + (KC),                            \
            &lds[(BUF) * 16384 + (H) * 8192 + w * 1024 + 512]);                \
  } while (0)

#define STG_B(H, BUF, KC) do {                                                 \
    gload16(Bsrc0 + (size_t)(H) * 128 * ldb + (KC),                            \
            &lds[32768 + (BUF) * 16384 + (H) * 8192 + w * 1024]);              \
    gload16(Bsrc1 + (size_t)(H) * 128 * ldb + (KC),                            \
            &lds[32768 + (BUF) * 16384 + (H) * 8192 + w * 1024 + 512]);        \
  } while (0)

#define DS_A(DST, MH) do {                                                     \
    const int abase = buf * 16384 + (MH) * 8192 + arow * 64;                   \
    _Pragma("unroll") for (int m = 0; m < 4; ++m) {                            \
      DST[m][0] = *(const bf16x8*)&lds[abase + m * 1024 + acol0];              \
      DST[m][1] = *(const bf16x8*)&lds[abase + m * 1024 + acol1];              \
    } } while (0)

#define DS_B(DST, NH) do {                                                     \
    const int bbase = 32768 + buf * 16384 + (NH) * 8192 + brow * 64;           \
    _Pragma("unroll") for (int n = 0; n < 2; ++n) {                            \
      DST[n][0] = *(const bf16x8*)&lds[bbase + n * 1024 + acol0];              \
      DST[n][1] = *(const bf16x8*)&lds[bbase + n * 1024 + acol1];              \
    } } while (0)

#define MFMA16(AI, AR, BR) do {                                                \
    _Pragma("unroll") for (int m = 0; m < 4; ++m)                              \
      _Pragma("unroll") for (int n = 0; n < 2; ++n) {                          \
        acc[AI][m][n] = __builtin_amdgcn_mfma_f32_16x16x32_bf16(               \
            AR[m][0], BR[n][0], acc[AI][m][n], 0, 0, 0);                       \
        acc[AI][m][n] = __builtin_amdgcn_mfma_f32_16x16x32_bf16(               \
            AR[m][1], BR[n][1], acc[AI][m][n], 0, 0, 0);                       \
      }                                                                        \
  } while (0)

template <int EPI>
__global__ __launch_bounds__(512, 2) void gemm256_k(
    const unsigned short* __restrict__ A, int lda,
    const unsigned short* __restrict__ B, int ldb,
    unsigned short* __restrict__ Cb, float* __restrict__ Cf,
    int M, int N, int Kext) {
  __shared__ unsigned short lds[65536];   // 128 KiB
  const int t = threadIdx.x, w = t >> 6, lane = t & 63;
  const int nbm = M >> 8, nbn = N >> 8, nwg = nbm * nbn;
  int id = blockIdx.x;
  id = (id & 7) * (nwg >> 3) + (id >> 3);           // XCD swizzle (nwg%8==0)
  const int bm = id % nbm, bn = id / nbm;
  const size_t m0 = (size_t)bm << 8, n0 = (size_t)bn << 8;
  const int koff = blockIdx.y * Kext;
  const int NT = Kext >> 6;
  const int scol = ((lane & 7) ^ (lane >> 3)) * 8;          // inverse swizzle
  const unsigned short* Asrc0 = A + (m0 + w * 16 + (lane >> 3)) * (size_t)lda + koff + scol;
  const unsigned short* Asrc1 = A + (m0 + w * 16 + 8 + (lane >> 3)) * (size_t)lda + koff + scol;
  const unsigned short* Bsrc0 = B + (n0 + w * 16 + (lane >> 3)) * (size_t)ldb + koff + scol;
  const unsigned short* Bsrc1 = B + (n0 + w * 16 + 8 + (lane >> 3)) * (size_t)ldb + koff + scol;
  const int arow = (w >> 2) * 64 + (lane & 15);
  const int brow = (w & 3) * 32 + (lane & 15);
  const int acol0 = ((lane >> 4) * 8) ^ ((lane & 7) << 3);  // swizzled read
  const int acol1 = acol0 ^ 32;
  f32x4 acc[4][4][2] = {};
  bf16x8 Acur[4][2], B0r[2][2], B1r[2][2];
  STG_A(0, 0, 0); STG_B(0, 0, 0); STG_A(1, 0, 0); STG_B(1, 0, 0);
  STG_A(0, 1, 64); STG_B(0, 1, 64);
  asm volatile("s_waitcnt vmcnt(4)" ::: "memory");
  __builtin_amdgcn_s_barrier();
  for (int kt = 0; kt < NT; ++kt) {
    const int buf = kt & 1;
    const int kc1 = (kt + 1) * 64, kc2 = (kt + 2) * 64;
    const bool p1 = (kt + 1 < NT), p2 = (kt + 2 < NT);
    // Phase A: quadrants (0,0),(0,1) — read A0,B0,B1; stage A1,B1(t+1)
    DS_A(Acur, 0); DS_B(B0r, 0); DS_B(B1r, 1);
    if (p1) { STG_A(1, buf ^ 1, kc1); STG_B(1, buf ^ 1, kc1); }
    __builtin_amdgcn_sched_barrier(0);
    __builtin_amdgcn_s_barrier();
    __builtin_amdgcn_s_setprio(1);
    MFMA16(0, Acur, B0r);
    MFMA16(1, Acur, B1r);
    __builtin_amdgcn_s_setprio(0);
    __builtin_amdgcn_sched_barrier(0);
    __builtin_amdgcn_s_barrier();
    // Phase B: quadrants (1,0),(1,1) — read A1; stage A0,B0(t+2)
    DS_A(Acur, 1);
    if (p2) { STG_A(0, buf, kc2); STG_B(0, buf, kc2); }
    __builtin_amdgcn_sched_barrier(0);
    __builtin_amdgcn_s_barrier();
    __builtin_amdgcn_s_setprio(1);
    MFMA16(2, Acur, B0r);
    MFMA16(3, Acur, B1r);
    __builtin_amdgcn_s_setprio(0);
    __builtin_amdgcn_sched_barrier(0);
    if (p2) { asm volatile("s_waitcnt vmcnt(4)" ::: "memory"); }
    else    { asm volatile("s_waitcnt vmcnt(0)" ::: "memory"); }
    __builtin_amdgcn_s_barrier();
  }
  // epilogue
#pragma unroll
  for (int Mh = 0; Mh < 2; ++Mh)
#pragma unroll
    for (int Nh = 0; Nh < 2; ++Nh)
#pragma unroll
      for (int m = 0; m < 4; ++m) {
        size_t gr = m0 + Mh * 128 + (w >> 2) * 64 + m * 16 + (lane >> 4) * 4;
        if constexpr (EPI == 2) {
          size_t gc = (n0 >> 1) + Nh * 64 + (w & 3) * 16 + (lane & 15);
          f32x4 v0 = acc[Mh * 2 + Nh][m][0];
          f32x4 v1 = acc[Mh * 2 + Nh][m][1];
#pragma unroll
          for (int j = 0; j < 4; ++j) {
            float s = v0[j] / (1.0f + __expf(-v0[j]));
            Cb[(gr + j) * (size_t)(N >> 1) + gc] = f2bf(s * v1[j]);
          }
        } else {
#pragma unroll
          for (int n = 0; n < 2; ++n) {
            size_t gc = n0 + Nh * 128 + (w & 3) * 32 + n * 16 + (lane & 15);
            f32x4 v = acc[Mh * 2 + Nh][m][n];
#pragma unroll
            for (int j = 0; j < 4; ++j) {
              size_t o = (gr + j) * (size_t)N + gc;
              if constexpr (EPI == 0) Cb[o] = f2bf(v[j]);
              else Cf[(size_t)blockIdx.y * M * N + o] = v[j];
            }
          }
        }
      }
}

// ---------- fused RoPE + V-transpose (flat grid; first 8192 blocks = RoPE) ----------
__global__ __launch_bounds__(256) void ropevt_k(const unsigned short* __restrict__ qkv,
    const float* __restrict__ freqs, unsigned short* __restrict__ Qr,
    unsigned short* __restrict__ Kr, unsigned short* __restrict__ Vt, int S) {
  if (blockIdx.x < 8192) {
    int idx = blockIdx.x * 256 + threadIdx.x;   // over S*16*64
    int dp = idx & 63, h = (idx >> 6) & 15, s = idx >> 10;
    float ang = freqs[s * 128 + dp];
    float c, sn;
    sincosf(ang, &sn, &c);
    size_t rq = (size_t)s * 6144 + h * 128 + dp;
    float q1 = bf2f(qkv[rq]),        q2 = bf2f(qkv[rq + 64]);
    float k1 = bf2f(qkv[rq + 2048]), k2 = bf2f(qkv[rq + 2048 + 64]);
    size_t ob = ((size_t)h * S + s) * 128 + dp;
    Qr[ob]      = f2bf(q1 * c - q2 * sn);
    Qr[ob + 64] = f2bf(q2 * c + q1 * sn);
    Kr[ob]      = f2bf(k1 * c - k2 * sn);
    Kr[ob + 64] = f2bf(k2 * c + k1 * sn);
  } else {
    __shared__ unsigned short tile[32][33];
    int vb = (int)blockIdx.x - 8192;            // 4096 blocks
    int h = vb >> 8, rem = vb & 255;
    int s0 = (rem & 63) * 32, d0 = (rem >> 6) * 32;
    int tx = threadIdx.x & 31, ty = threadIdx.x >> 5;
#pragma unroll
    for (int i = 0; i < 4; ++i)
      tile[ty + i * 8][tx] = qkv[(size_t)(s0 + ty + i * 8) * 6144 + 4096 + h * 128 + d0 + tx];
    __syncthreads();
#pragma unroll
    for (int i = 0; i < 4; ++i)
      Vt[((size_t)h * 128 + d0 + ty + i * 8) * S + s0 + tx] = tile[tx][ty + i * 8];
  }
}

// ---------- causal flash attention with alibi, 1-tile software pipeline ----------
// Diagonal-only masking; defer-max (THR=8); setprio around MFMA clusters.
#define STGKV(KT, BUF) do {                                                    \
    _Pragma("unroll") for (int it = 0; it < 4; ++it)                           \
      gload16(Kb + (size_t)((KT) * 64 + it * 16 + sr) * 128 + scw,             \
              &lds[(BUF) * 8192 + (it * 16 + wave * 4) * 128]);                \
    _Pragma("unroll") for (int it = 0; it < 4; ++it)                           \
      gload16(Vb + (size_t)(it * 32 + vr) * S + (KT) * 64 + vcw,               \
              &lds[16384 + (BUF) * 8192 + (it * 32 + wave * 8) * 64]);         \
  } while (0)

#define ATTN_TILE(CUR, NXT, KT) do {                                           \
    const int buf = (KT) & 1;                                                  \
    const bool p1 = ((KT) + 1 < ktiles);                                       \
    if (p1) {                                                                  \
      STGKV((KT) + 1, buf ^ 1);                                                \
      _Pragma("unroll") for (int q8 = 0; q8 < 16; ++q8)                        \
        NXT[q8] = albase[(size_t)(q8 & 3) * S + ((KT) + 1) * 64 + (q8 >> 2) * 16]; \
      asm volatile("s_waitcnt vmcnt(24)" ::: "memory");                        \
    } else {                                                                   \
      asm volatile("s_waitcnt vmcnt(0)" ::: "memory");                         \
    }                                                                          \
    __builtin_amdgcn_s_barrier();                                              \
    f32x4 sf[4] = {};                                                          \
    __builtin_amdgcn_s_setprio(1);                                             \
    _Pragma("unroll") for (int ks = 0; ks < 4; ++ks)                           \
      _Pragma("unroll") for (int n = 0; n < 4; ++n) {                          \
        bf16x8 kf = *(const bf16x8*)&lds[buf * 8192 + (n * 16 + row) * 128 +   \
                                         ((ks * 32 + kg) ^ kswz)];             \
        sf[n] = __builtin_amdgcn_mfma_f32_16x16x32_bf16(qf[ks], kf, sf[n], 0, 0, 0); \
      }                                                                        \
    __builtin_amdgcn_s_setprio(0);                                             \
    float pv[4][4];                                                            \
    float tmax[4] = {-1e30f, -1e30f, -1e30f, -1e30f};                          \
    if ((KT) == ktiles - 1) {                                                  \
      _Pragma("unroll") for (int n = 0; n < 4; ++n) {                          \
        int k_abs = (KT) * 64 + n * 16 + col;                                  \
        _Pragma("unroll") for (int j = 0; j < 4; ++j) {                        \
          int q_abs = q0 + wave * 16 + cg * 4 + j;                             \
          float v = sf[n][j] * scale + CUR[n * 4 + j];                         \
          if (k_abs > q_abs) v = -1e30f;                                       \
          pv[n][j] = v;                                                        \
          tmax[j] = fmaxf(tmax[j], v);                                         \
        } }                                                                    \
    } else {                                                                   \
      _Pragma("unroll") for (int n = 0; n < 4; ++n)                            \
        _Pragma("unroll") for (int j = 0; j < 4; ++j) {                        \
          float v = sf[n][j] * scale + CUR[n * 4 + j];                         \
          pv[n][j] = v;                                                        \
          tmax[j] = fmaxf(tmax[j], v);                                         \
        }                                                                      \
    }                                                                          \
    _Pragma("unroll") for (int o2 = 1; o2 < 16; o2 <<= 1)                      \
      _Pragma("unroll") for (int j = 0; j < 4; ++j)                            \
        tmax[j] = fmaxf(tmax[j], __shfl_xor(tmax[j], o2, 64));                 \
    float rsum[4] = {};                                                        \
    float md = fmaxf(fmaxf(tmax[0] - m_run[0], tmax[1] - m_run[1]),            \
                     fmaxf(tmax[2] - m_run[2], tmax[3] - m_run[3]));           \
    if (__all(md <= 8.0f)) {                                                   \
      _Pragma("unroll") for (int n = 0; n < 4; ++n)                            \
        _Pragma("unroll") for (int j = 0; j < 4; ++j) {                        \
          float p = __expf(pv[n][j] - m_run[j]);                               \
          pv[n][j] = p;  rsum[j] += p;                                         \
        }                                                                      \
      _Pragma("unroll") for (int o2 = 1; o2 < 16; o2 <<= 1)                    \
        _Pragma("unroll") for (int j = 0; j < 4; ++j)                          \
          rsum[j] += __shfl_xor(rsum[j], o2, 64);                              \
      _Pragma("unroll") for (int j = 0; j < 4; ++j) l_run[j] += rsum[j];       \
    } else {                                                                   \
      float alpha[4];                                                          \
      _Pragma("unroll") for (int j = 0; j < 4; ++j) {                          \
        float mn = fmaxf(m_run[j], tmax[j]);                                   \
        alpha[j] = __expf(m_run[j] - mn);                                      \
        m_run[j] = mn;                                                         \
      }                                                                        \
      _Pragma("unroll") for (int n = 0; n < 4; ++n)                            \
        _Pragma("unroll") for (int j = 0; j < 4; ++j) {                        \
          float p = __expf(pv[n][j] - m_run[j]);                               \
          pv[n][j] = p;  rsum[j] += p;                                         \
        }                                                                      \
      _Pragma("unroll") for (int o2 = 1; o2 < 16; o2 <<= 1)                    \
        _Pragma("unroll") for (int j = 0; j < 4; ++j)                          \
          rsum[j] += __shfl_xor(rsum[j], o2, 64);                              \
      _Pragma("unroll") for (int j = 0; j < 4; ++j)                            \
        l_run[j] = l_run[j] * alpha[j] + rsum[j];                              \
      _Pragma("unroll") for (int nn = 0; nn < 8; ++nn)                         \
        _Pragma("unroll") for (int j = 0; j < 4; ++j) o[nn][j] *= alpha[j];    \
    }                                                                          \
    _Pragma("unroll") for (int n = 0; n < 4; ++n)                              \
      _Pragma("unroll") for (int j = 0; j < 4; ++j) {                          \
        int pr = cg * 4 + j;                                                   \
        pw[pr * 64 + ((n * 16 + col) ^ ((pr & 7) << 3))] = f2bf(pv[n][j]);     \
      }                                                                        \
    asm volatile("s_waitcnt lgkmcnt(0)" ::: "memory");                         \
    __builtin_amdgcn_sched_barrier(0);                                         \
    __builtin_amdgcn_s_setprio(1);                                             \
    _Pragma("unroll") for (int kk = 0; kk < 2; ++kk) {                         \
      bf16x8 pf = *(const bf16x8*)&pw[row * 64 + ((kk * 32 + kg) ^ kswz)];     \
      _Pragma("unroll") for (int nn = 0; nn < 8; ++nn) {                       \
        bf16x8 vf = *(const bf16x8*)&lds[16384 + buf * 8192 +                  \
                                         (nn * 16 + row) * 64 +                \
                                         ((kk * 32 + kg) ^ kswz)];             \
        o[nn] = __builtin_amdgcn_mfma_f32_16x16x32_bf16(pf, vf, o[nn], 0, 0, 0); \
      } }                                                                      \
    __builtin_amdgcn_s_setprio(0);                                             \
    __builtin_amdgcn_s_barrier();                                              \
  } while (0)

__global__ __launch_bounds__(256) void attn_k(
    const unsigned short* __restrict__ Qr, const unsigned short* __restrict__ Kr,
    const unsigned short* __restrict__ Vt, const float* __restrict__ alibi,
    unsigned short* __restrict__ Ao, int S) {
  __shared__ unsigned short lds[36864];   // 72 KiB
  const int t = threadIdx.x, wave = t >> 6, lane = t & 63;
  const int h = blockIdx.y, nq = gridDim.x, bx = blockIdx.x;
  const int qt = (bx & 1) ? (nq - 1 - (bx >> 1)) : (bx >> 1);  // balance pairs
  const int q0 = qt * 64;
  const int sr = t >> 4, scw = ((t & 15) ^ ((t >> 4) & 7)) * 8;
  const int vr = t >> 3, vcw = ((t & 7) ^ ((t >> 3) & 7)) * 8;
  const unsigned short* Kb = Kr + (size_t)h * S * 128;
  const unsigned short* Vb = Vt + (size_t)h * 128 * S;
  const int row = lane & 15, kg = (lane >> 4) * 8, cg = lane >> 4, col = lane & 15;
  const int kswz = (lane & 7) << 3;
  bf16x8 qf[4];
  const unsigned short* Qrow = Qr + ((size_t)h * S + q0 + wave * 16 + row) * 128;
#pragma unroll
  for (int ks = 0; ks < 4; ++ks) qf[ks] = *(const bf16x8*)&Qrow[ks * 32 + kg];
  f32x4 o[8] = {};
  float m_run[4] = {-1e30f, -1e30f, -1e30f, -1e30f};
  float l_run[4] = {};
  unsigned short* pw = &lds[32768 + wave * 1024];
  const float scale = 0.08838834764831843f;
  const int ktiles = qt + 1;
  const float* albase = alibi + (size_t)h * S * S +
                        ((size_t)q0 + wave * 16 + cg * 4) * S + col;
  float alA[16], alB[16];
  STGKV(0, 0);
#pragma unroll
  for (int q8 = 0; q8 < 16; ++q8)
    alA[q8] = albase[(size_t)(q8 & 3) * S + (q8 >> 2) * 16];
  for (int kt = 0; kt < ktiles; kt += 2) {
    ATTN_TILE(alA, alB, kt);
    if (kt + 1 < ktiles) ATTN_TILE(alB, alA, kt + 1);
  }
#pragma unroll
  for (int nn = 0; nn < 8; ++nn)
#pragma unroll
    for (int j = 0; j < 4; ++j) {
      int q_abs = q0 + wave * 16 + cg * 4 + j;
      Ao[(size_t)q_abs * 2048 + h * 128 + nn * 16 + col] = f2bf(o[nn][j] / l_run[j]);
    }
}

// ---------- split-K reduce + residual: out = resid + sum_s part[s] ----------
__global__ __launch_bounds__(256) void reduce4_k(const float* __restrict__ part,
    const float* __restrict__ resid, float* __restrict__ out, int n4, size_t mn) {
  int i = blockIdx.x * 256 + threadIdx.x;
  if (i >= n4) return;
  const float4* p = (const float4*)part;
  size_t q = mn >> 2;
  float4 a = ((const float4*)resid)[i];
  float4 s0 = p[i], s1 = p[i + q], s2 = p[i + 2 * q], s3 = p[i + 3 * q];
  float4 r;
  r.x = a.x + s0.x + s1.x + s2.x + s3.x;
  r.y = a.y + s0.y + s1.y + s2.y + s3.y;
  r.z = a.z + s0.z + s1.z + s2.z + s3.z;
  r.w = a.w + s0.w + s1.w + s2.w + s3.w;
  ((float4*)out)[i] = r;
}

// ---------- host ----------
extern "C" void kernel_launch(void* const* d_in, const int* in_sizes, int n_in,
                              void* d_out, int out_size, void* d_ws, size_t ws_size,
                              hipStream_t stream) {
  const int S = 2048, H = 2048, NH = 16, DH = 128, FF = 8192;
  const float* x     = (const float*)d_in[0];
  const float* alibi = (const float*)d_in[2];
  const float* freqs = (const float*)d_in[3];
  const float* wq    = (const float*)d_in[4];
  const float* wk    = (const float*)d_in[5];
  const float* wv    = (const float*)d_in[6];
  const float* wo    = (const float*)d_in[7];
  const float* w1    = (const float*)d_in[8];
  const float* w2    = (const float*)d_in[9];
  const float* w3    = (const float*)d_in[10];
  const float* anw   = (const float*)d_in[11];
  const float* fnw   = (const float*)d_in[12];
  float* out = (float*)d_out;

  char* ws = (char*)d_ws;
  size_t off = 0;
  auto alloc = [&](size_t n) { char* p = ws + off; off += (n + 255) & ~(size_t)255; return p; };
  unsigned short* qkvT = (unsigned short*)alloc((size_t)3 * H * H * 2);
  unsigned short* woT  = (unsigned short*)alloc((size_t)H * H * 2);
  unsigned short* w13T = (unsigned short*)alloc((size_t)2 * FF * H * 2);
  unsigned short* w2T  = (unsigned short*)alloc((size_t)H * FF * 2);
  float*          x2   = (float*)alloc((size_t)S * H * 4);
  unsigned short* nx2  = (unsigned short*)alloc((size_t)S * H * 2);
  unsigned short* gbuf = (unsigned short*)alloc((size_t)S * FF * 2);
  unsigned short* nx   = (unsigned short*)alloc((size_t)S * H * 2);
  unsigned short* qkvb = (unsigned short*)alloc((size_t)S * 3 * H * 2);
  unsigned short* Qr   = (unsigned short*)alloc((size_t)NH * S * DH * 2);
  unsigned short* Kr   = (unsigned short*)alloc((size_t)NH * S * DH * 2);
  unsigned short* Vt   = (unsigned short*)alloc((size_t)NH * DH * S * 2);
  unsigned short* attno= (unsigned short*)alloc((size_t)S * H * 2);
  float* part4 = (float*)alloc((size_t)4 * S * H * 4);   // split-K partials

  wtrans4_k<<<dim3(32, 32, 4), 256, 0, stream>>>(
      wq, wk, wv, wo,
      qkvT, qkvT + (size_t)H * H, qkvT + (size_t)2 * H * H, woT, H, H);
  wtrans13_k<<<dim3(128, 32, 2), 256, 0, stream>>>(w1, w3, w13T, H, FF);
  wtrans64_k<<<dim3(32, 128), 256, 0, stream>>>(w2, w2T, FF, H, -1);

  rmsnorm_k<<<S, 256, 0, stream>>>(x, anw, nx, H);
  gemm256_k<0><<<dim3(192, 1), 512, 0, stream>>>(nx, H, qkvT, H, qkvb, nullptr, S, 3 * H, H);
  ropevt_k<<<12288, 256, 0, stream>>>(qkvb, freqs, Qr, Kr, Vt, S);
  attn_k<<<dim3(S / 64, NH), 256, 0, stream>>>(Qr, Kr, Vt, alibi, attno, S);
  // wo GEMM: split-K x4 on the 256^2 kernel (256 blocks), f32 partials
  gemm256_k<1><<<dim3(64, 4), 512, 0, stream>>>(attno, H, woT, H, nullptr, part4, S, H, 512);
  // fused: x2 = x + sum(partials); nx2 = rmsnorm(x2, fnw)
  reduce4rms_k<<<S, 256, 0, stream>>>(part4, x, fnw, x2, nx2, H, (size_t)S * H);
  gemm256_k<2><<<dim3(512, 1), 512, 0, stream>>>(nx2, H, w13T, H, gbuf, nullptr, S, 2 * FF, H);
  gemm256_k<1><<<dim3(64, 4), 512, 0, stream>>>(gbuf, FF, w2T, FF, nullptr, part4, S, H, FF / 4);
  reduce4_k<<<4096, 256, 0, stream>>>(part4, x2, out, S * H / 4, (size_t)S * H);
}

// Round 18
// 510.805 us; speedup vs baseline: 1.1062x; 1.1062x over previous
//
#include <hip/hip_runtime.h>
#include <hip/hip_bf16.h>
#include <math.h>

// ---------- helpers ----------
typedef __bf16 bf16x8 __attribute__((ext_vector_type(8)));
typedef float  f32x4  __attribute__((ext_vector_type(4)));
typedef unsigned short u16x8 __attribute__((ext_vector_type(8)));
typedef unsigned short u16x4 __attribute__((ext_vector_type(4)));

#define DEV static __device__ __forceinline__

DEV void gload16(const void* g, void* l) {
  __builtin_amdgcn_global_load_lds((__attribute__((address_space(1))) void*)g,
                                   (__attribute__((address_space(3))) void*)l,
                                   16, 0, 0);
}

DEV float bf2f(unsigned short u) {
  unsigned v = ((unsigned)u) << 16;
  return __builtin_bit_cast(float, v);
}
DEV unsigned short f2bf(float f) {
  unsigned u = __builtin_bit_cast(unsigned, f);
  u = u + 0x7fffu + ((u >> 16) & 1u);   // round-to-nearest-even
  return (unsigned short)(u >> 16);
}

// ---------- rmsnorm: fp32 [S,H] -> bf16 [S,H] ----------
__global__ __launch_bounds__(256) void rmsnorm_k(const float* __restrict__ x,
    const float* __restrict__ w, unsigned short* __restrict__ out, int H) {
  int row = blockIdx.x;
  const float4* xr = (const float4*)(x + (size_t)row * H);
  float4 a = xr[threadIdx.x * 2], b = xr[threadIdx.x * 2 + 1];
  float ss = a.x*a.x + a.y*a.y + a.z*a.z + a.w*a.w
           + b.x*b.x + b.y*b.y + b.z*b.z + b.w*b.w;
#pragma unroll
  for (int o = 32; o; o >>= 1) ss += __shfl_down(ss, o, 64);
  __shared__ float red[4];
  if ((threadIdx.x & 63) == 0) red[threadIdx.x >> 6] = ss;
  __syncthreads();
  float rs = rsqrtf((red[0] + red[1] + red[2] + red[3]) * (1.0f / 2048.0f) + 1e-5f);
  size_t base = (size_t)row * H + threadIdx.x * 8;
  const float* wv = w + threadIdx.x * 8;
  float vals[8] = {a.x, a.y, a.z, a.w, b.x, b.y, b.z, b.w};
  u16x8 o8;
#pragma unroll
  for (int i = 0; i < 8; ++i) o8[i] = f2bf(vals[i] * rs * wv[i]);
  *(u16x8*)(out + base) = o8;
}

// ---------- split-K reduce + residual + rmsnorm (wo path) ----------
__global__ __launch_bounds__(256) void reduce4rms_k(const float* __restrict__ part,
    const float* __restrict__ resid, const float* __restrict__ w,
    float* __restrict__ x2, unsigned short* __restrict__ nxo, int H, size_t mn) {
  const int row = blockIdx.x, t = threadIdx.x;
  size_t base = (size_t)row * H + t * 8;
  float v[8];
  {
    float4 a = ((const float4*)(resid + base))[0];
    float4 b = ((const float4*)(resid + base))[1];
    v[0]=a.x; v[1]=a.y; v[2]=a.z; v[3]=a.w; v[4]=b.x; v[5]=b.y; v[6]=b.z; v[7]=b.w;
  }
#pragma unroll
  for (int s = 0; s < 4; ++s) {
    const float4* p4 = (const float4*)(part + (size_t)s * mn + base);
    float4 pa = p4[0], pb = p4[1];
    v[0]+=pa.x; v[1]+=pa.y; v[2]+=pa.z; v[3]+=pa.w;
    v[4]+=pb.x; v[5]+=pb.y; v[6]+=pb.z; v[7]+=pb.w;
  }
  float ss = 0.f;
#pragma unroll
  for (int i = 0; i < 8; ++i) ss += v[i] * v[i];
  float4 o0 = {v[0],v[1],v[2],v[3]}, o1 = {v[4],v[5],v[6],v[7]};
  ((float4*)(x2 + base))[0] = o0;
  ((float4*)(x2 + base))[1] = o1;
#pragma unroll
  for (int o = 32; o; o >>= 1) ss += __shfl_down(ss, o, 64);
  __shared__ float red[4];
  if ((t & 63) == 0) red[t >> 6] = ss;
  __syncthreads();
  float rs = rsqrtf((red[0] + red[1] + red[2] + red[3]) * (1.0f / 2048.0f) + 1e-5f);
  const float* wv = w + t * 8;
  u16x8 o8;
#pragma unroll
  for (int i = 0; i < 8; ++i) o8[i] = f2bf(v[i] * rs * wv[i]);
  *(u16x8*)(nxo + base) = o8;
}

// ---------- transpose+convert core: 64x64 tile ----------
DEV void wtrans_body(const float* __restrict__ W, unsigned short* __restrict__ Wt,
                     int R, int C, int ilv, int bx, int by, int t,
                     unsigned short (*tile)[68]) {
  const int c0 = bx * 64, r0 = by * 64;
  const int lr = t >> 4, lc4 = (t & 15) * 4;
#pragma unroll
  for (int i = 0; i < 4; ++i) {
    float4 v = *(const float4*)&W[(size_t)(r0 + lr + i * 16) * C + c0 + lc4];
    u16x4 s4;
    s4[0] = f2bf(v.x); s4[1] = f2bf(v.y); s4[2] = f2bf(v.z); s4[3] = f2bf(v.w);
    *(u16x4*)&tile[lr + i * 16][lc4] = s4;
  }
  __syncthreads();
  const int oc = t >> 3, seg = (t & 7) * 8;
#pragma unroll
  for (int i = 0; i < 2; ++i) {
    int c = c0 + oc + i * 32;
    u16x8 o8;
#pragma unroll
    for (int j = 0; j < 8; ++j) o8[j] = tile[seg + j][oc + i * 32];
    size_t dstrow = (ilv < 0) ? (size_t)c
                              : (size_t)(c >> 4) * 32 + (c & 15) + ilv * 16;
    *(u16x8*)&Wt[dstrow * R + r0 + seg] = o8;
  }
}

__global__ __launch_bounds__(256) void wtrans64_k(const float* __restrict__ W,
    unsigned short* __restrict__ Wt, int R, int C, int ilv) {
  __shared__ unsigned short tile[64][68];
  wtrans_body(W, Wt, R, C, ilv, blockIdx.x, blockIdx.y, threadIdx.x, tile);
}

__global__ __launch_bounds__(256) void wtrans4_k(
    const float* __restrict__ s0, const float* __restrict__ s1,
    const float* __restrict__ s2, const float* __restrict__ s3,
    unsigned short* __restrict__ d0, unsigned short* __restrict__ d1,
    unsigned short* __restrict__ d2, unsigned short* __restrict__ d3,
    int R, int C) {
  __shared__ unsigned short tile[64][68];
  const float* s = (blockIdx.z == 0) ? s0 : (blockIdx.z == 1) ? s1
                 : (blockIdx.z == 2) ? s2 : s3;
  unsigned short* d = (blockIdx.z == 0) ? d0 : (blockIdx.z == 1) ? d1
                    : (blockIdx.z == 2) ? d2 : d3;
  wtrans_body(s, d, R, C, -1, blockIdx.x, blockIdx.y, threadIdx.x, tile);
}

__global__ __launch_bounds__(256) void wtrans13_k(
    const float* __restrict__ w1, const float* __restrict__ w3,
    unsigned short* __restrict__ dst, int R, int C) {
  __shared__ unsigned short tile[64][68];
  const float* s = blockIdx.z ? w3 : w1;
  wtrans_body(s, dst, R, C, (int)blockIdx.z, blockIdx.x, blockIdx.y,
              threadIdx.x, tile);
}

// ============ 256x256 GEMM, 16x16x32 MFMA, 2-phase fragment-reuse ============
#define STG_A(H, BUF, KC) do {                                                 \
    gload16(Asrc0 + (size_t)(H) * 128 * lda + (KC),                            \
            &lds[(BUF) * 16384 + (H) * 8192 + w * 1024]);                      \
    gload16(Asrc1 + (size_t)(H) * 128 * lda + (KC),                            \
            &lds[(BUF) * 16384 + (H) * 8192 + w * 1024 + 512]);                \
  } while (0)

#define STG_B(H, BUF, KC) do {                                                 \
    gload16(Bsrc0 + (size_t)(H) * 128 * ldb + (KC),                            \
            &lds[32768 + (BUF) * 16384 + (H) * 8192 + w * 1024]);              \
    gload16(Bsrc1 + (size_t)(H) * 128 * ldb + (KC),                            \
            &lds[32768 + (BUF) * 16384 + (H) * 8192 + w * 1024 + 512]);        \
  } while (0)

#define DS_A(DST, MH) do {                                                     \
    const int abase = buf * 16384 + (MH) * 8192 + arow * 64;                   \
    _Pragma("unroll") for (int m = 0; m < 4; ++m) {                            \
      DST[m][0] = *(const bf16x8*)&lds[abase + m * 1024 + acol0];              \
      DST[m][1] = *(const bf16x8*)&lds[abase + m * 1024 + acol1];              \
    } } while (0)

#define DS_B(DST, NH) do {                                                     \
    const int bbase = 32768 + buf * 16384 + (NH) * 8192 + brow * 64;           \
    _Pragma("unroll") for (int n = 0; n < 2; ++n) {                            \
      DST[n][0] = *(const bf16x8*)&lds[bbase + n * 1024 + acol0];              \
      DST[n][1] = *(const bf16x8*)&lds[bbase + n * 1024 + acol1];              \
    } } while (0)

#define MFMA16(AI, AR, BR) do {                                                \
    _Pragma("unroll") for (int m = 0; m < 4; ++m)                              \
      _Pragma("unroll") for (int n = 0; n < 2; ++n) {                          \
        acc[AI][m][n] = __builtin_amdgcn_mfma_f32_16x16x32_bf16(               \
            AR[m][0], BR[n][0], acc[AI][m][n], 0, 0, 0);                       \
        acc[AI][m][n] = __builtin_amdgcn_mfma_f32_16x16x32_bf16(               \
            AR[m][1], BR[n][1], acc[AI][m][n], 0, 0, 0);                       \
      }                                                                        \
  } while (0)

template <int EPI>
__global__ __launch_bounds__(512, 2) void gemm256_k(
    const unsigned short* __restrict__ A, int lda,
    const unsigned short* __restrict__ B, int ldb,
    unsigned short* __restrict__ Cb, float* __restrict__ Cf,
    int M, int N, int Kext) {
  __shared__ unsigned short lds[65536];   // 128 KiB
  const int t = threadIdx.x, w = t >> 6, lane = t & 63;
  const int nbm = M >> 8, nbn = N >> 8, nwg = nbm * nbn;
  int id = blockIdx.x;
  id = (id & 7) * (nwg >> 3) + (id >> 3);           // XCD swizzle (nwg%8==0)
  const int bm = id % nbm, bn = id / nbm;
  const size_t m0 = (size_t)bm << 8, n0 = (size_t)bn << 8;
  const int koff = blockIdx.y * Kext;
  const int NT = Kext >> 6;
  const int scol = ((lane & 7) ^ (lane >> 3)) * 8;          // inverse swizzle
  const unsigned short* Asrc0 = A + (m0 + w * 16 + (lane >> 3)) * (size_t)lda + koff + scol;
  const unsigned short* Asrc1 = A + (m0 + w * 16 + 8 + (lane >> 3)) * (size_t)lda + koff + scol;
  const unsigned short* Bsrc0 = B + (n0 + w * 16 + (lane >> 3)) * (size_t)ldb + koff + scol;
  const unsigned short* Bsrc1 = B + (n0 + w * 16 + 8 + (lane >> 3)) * (size_t)ldb + koff + scol;
  const int arow = (w >> 2) * 64 + (lane & 15);
  const int brow = (w & 3) * 32 + (lane & 15);
  const int acol0 = ((lane >> 4) * 8) ^ ((lane & 7) << 3);  // swizzled read
  const int acol1 = acol0 ^ 32;
  f32x4 acc[4][4][2] = {};
  bf16x8 Acur[4][2], B0r[2][2], B1r[2][2];
  STG_A(0, 0, 0); STG_B(0, 0, 0); STG_A(1, 0, 0); STG_B(1, 0, 0);
  STG_A(0, 1, 64); STG_B(0, 1, 64);
  asm volatile("s_waitcnt vmcnt(4)" ::: "memory");
  __builtin_amdgcn_s_barrier();
  for (int kt = 0; kt < NT; ++kt) {
    const int buf = kt & 1;
    const int kc1 = (kt + 1) * 64, kc2 = (kt + 2) * 64;
    const bool p1 = (kt + 1 < NT), p2 = (kt + 2 < NT);
    // Phase A: quadrants (0,0),(0,1) — read A0,B0,B1; stage A1,B1(t+1)
    DS_A(Acur, 0); DS_B(B0r, 0); DS_B(B1r, 1);
    if (p1) { STG_A(1, buf ^ 1, kc1); STG_B(1, buf ^ 1, kc1); }
    __builtin_amdgcn_sched_barrier(0);
    __builtin_amdgcn_s_barrier();
    __builtin_amdgcn_s_setprio(1);
    MFMA16(0, Acur, B0r);
    MFMA16(1, Acur, B1r);
    __builtin_amdgcn_s_setprio(0);
    __builtin_amdgcn_sched_barrier(0);
    __builtin_amdgcn_s_barrier();
    // Phase B: quadrants (1,0),(1,1) — read A1; stage A0,B0(t+2)
    DS_A(Acur, 1);
    if (p2) { STG_A(0, buf, kc2); STG_B(0, buf, kc2); }
    __builtin_amdgcn_sched_barrier(0);
    __builtin_amdgcn_s_barrier();
    __builtin_amdgcn_s_setprio(1);
    MFMA16(2, Acur, B0r);
    MFMA16(3, Acur, B1r);
    __builtin_amdgcn_s_setprio(0);
    __builtin_amdgcn_sched_barrier(0);
    if (p2) { asm volatile("s_waitcnt vmcnt(4)" ::: "memory"); }
    else    { asm volatile("s_waitcnt vmcnt(0)" ::: "memory"); }
    __builtin_amdgcn_s_barrier();
  }
  // epilogue
#pragma unroll
  for (int Mh = 0; Mh < 2; ++Mh)
#pragma unroll
    for (int Nh = 0; Nh < 2; ++Nh)
#pragma unroll
      for (int m = 0; m < 4; ++m) {
        size_t gr = m0 + Mh * 128 + (w >> 2) * 64 + m * 16 + (lane >> 4) * 4;
        if constexpr (EPI == 2) {
          size_t gc = (n0 >> 1) + Nh * 64 + (w & 3) * 16 + (lane & 15);
          f32x4 v0 = acc[Mh * 2 + Nh][m][0];
          f32x4 v1 = acc[Mh * 2 + Nh][m][1];
#pragma unroll
          for (int j = 0; j < 4; ++j) {
            float s = v0[j] / (1.0f + __expf(-v0[j]));
            Cb[(gr + j) * (size_t)(N >> 1) + gc] = f2bf(s * v1[j]);
          }
        } else {
#pragma unroll
          for (int n = 0; n < 2; ++n) {
            size_t gc = n0 + Nh * 128 + (w & 3) * 32 + n * 16 + (lane & 15);
            f32x4 v = acc[Mh * 2 + Nh][m][n];
#pragma unroll
            for (int j = 0; j < 4; ++j) {
              size_t o = (gr + j) * (size_t)N + gc;
              if constexpr (EPI == 0) Cb[o] = f2bf(v[j]);
              else Cf[(size_t)blockIdx.y * M * N + o] = v[j];
            }
          }
        }
      }
}

// ---------- fused RoPE + V-transpose (flat grid; first 8192 blocks = RoPE) ----------
__global__ __launch_bounds__(256) void ropevt_k(const unsigned short* __restrict__ qkv,
    const float* __restrict__ freqs, unsigned short* __restrict__ Qr,
    unsigned short* __restrict__ Kr, unsigned short* __restrict__ Vt, int S) {
  if (blockIdx.x < 8192) {
    int idx = blockIdx.x * 256 + threadIdx.x;   // over S*16*64
    int dp = idx & 63, h = (idx >> 6) & 15, s = idx >> 10;
    float ang = freqs[s * 128 + dp];
    float c, sn;
    sincosf(ang, &sn, &c);
    size_t rq = (size_t)s * 6144 + h * 128 + dp;
    float q1 = bf2f(qkv[rq]),        q2 = bf2f(qkv[rq + 64]);
    float k1 = bf2f(qkv[rq + 2048]), k2 = bf2f(qkv[rq + 2048 + 64]);
    size_t ob = ((size_t)h * S + s) * 128 + dp;
    Qr[ob]      = f2bf(q1 * c - q2 * sn);
    Qr[ob + 64] = f2bf(q2 * c + q1 * sn);
    Kr[ob]      = f2bf(k1 * c - k2 * sn);
    Kr[ob + 64] = f2bf(k2 * c + k1 * sn);
  } else {
    __shared__ unsigned short tile[32][33];
    int vb = (int)blockIdx.x - 8192;            // 4096 blocks
    int h = vb >> 8, rem = vb & 255;
    int s0 = (rem & 63) * 32, d0 = (rem >> 6) * 32;
    int tx = threadIdx.x & 31, ty = threadIdx.x >> 5;
#pragma unroll
    for (int i = 0; i < 4; ++i)
      tile[ty + i * 8][tx] = qkv[(size_t)(s0 + ty + i * 8) * 6144 + 4096 + h * 128 + d0 + tx];
    __syncthreads();
#pragma unroll
    for (int i = 0; i < 4; ++i)
      Vt[((size_t)h * 128 + d0 + ty + i * 8) * S + s0 + tx] = tile[tx][ty + i * 8];
  }
}

// ---------- causal flash attention with alibi, 1-tile software pipeline ----------
// (round-16 body: 88 VGPR, 2 blocks/CU — defer-max/diag/setprio reverted)
#define STGKV(KT, BUF) do {                                                    \
    _Pragma("unroll") for (int it = 0; it < 4; ++it)                           \
      gload16(Kb + (size_t)((KT) * 64 + it * 16 + sr) * 128 + scw,             \
              &lds[(BUF) * 8192 + (it * 16 + wave * 4) * 128]);                \
    _Pragma("unroll") for (int it = 0; it < 4; ++it)                           \
      gload16(Vb + (size_t)(it * 32 + vr) * S + (KT) * 64 + vcw,               \
              &lds[16384 + (BUF) * 8192 + (it * 32 + wave * 8) * 64]);         \
  } while (0)

#define ATTN_TILE(CUR, NXT, KT) do {                                           \
    const int buf = (KT) & 1;                                                  \
    const bool p1 = ((KT) + 1 < ktiles);                                       \
    if (p1) {                                                                  \
      STGKV((KT) + 1, buf ^ 1);                                                \
      _Pragma("unroll") for (int q8 = 0; q8 < 16; ++q8)                        \
        NXT[q8] = albase[(size_t)(q8 & 3) * S + ((KT) + 1) * 64 + (q8 >> 2) * 16]; \
      asm volatile("s_waitcnt vmcnt(24)" ::: "memory");                        \
    } else {                                                                   \
      asm volatile("s_waitcnt vmcnt(0)" ::: "memory");                         \
    }                                                                          \
    __builtin_amdgcn_s_barrier();                                              \
    f32x4 sf[4] = {};                                                          \
    _Pragma("unroll") for (int ks = 0; ks < 4; ++ks)                           \
      _Pragma("unroll") for (int n = 0; n < 4; ++n) {                          \
        bf16x8 kf = *(const bf16x8*)&lds[buf * 8192 + (n * 16 + row) * 128 +   \
                                         ((ks * 32 + kg) ^ kswz)];             \
        sf[n] = __builtin_amdgcn_mfma_f32_16x16x32_bf16(qf[ks], kf, sf[n], 0, 0, 0); \
      }                                                                        \
    float pv[4][4];                                                            \
    float tmax[4] = {-1e30f, -1e30f, -1e30f, -1e30f};                          \
    _Pragma("unroll") for (int n = 0; n < 4; ++n) {                            \
      int k_abs = (KT) * 64 + n * 16 + col;                                    \
      _Pragma("unroll") for (int j = 0; j < 4; ++j) {                          \
        int q_abs = q0 + wave * 16 + cg * 4 + j;                               \
        float v = sf[n][j] * scale + CUR[n * 4 + j];                           \
        if (k_abs > q_abs) v = -1e30f;                                         \
        pv[n][j] = v;                                                          \
        tmax[j] = fmaxf(tmax[j], v);                                           \
      } }                                                                      \
    _Pragma("unroll") for (int o2 = 1; o2 < 16; o2 <<= 1)                      \
      _Pragma("unroll") for (int j = 0; j < 4; ++j)                            \
        tmax[j] = fmaxf(tmax[j], __shfl_xor(tmax[j], o2, 64));                 \
    float alpha[4], rsum[4] = {};                                              \
    _Pragma("unroll") for (int j = 0; j < 4; ++j) {                            \
      float mn = fmaxf(m_run[j], tmax[j]);                                     \
      alpha[j] = __expf(m_run[j] - mn);                                        \
      m_run[j] = mn;                                                           \
    }                                                                          \
    _Pragma("unroll") for (int n = 0; n < 4; ++n)                              \
      _Pragma("unroll") for (int j = 0; j < 4; ++j) {                          \
        float p = __expf(pv[n][j] - m_run[j]);                                 \
        pv[n][j] = p;                                                          \
        rsum[j] += p;                                                          \
      }                                                                        \
    _Pragma("unroll") for (int o2 = 1; o2 < 16; o2 <<= 1)                      \
      _Pragma("unroll") for (int j = 0; j < 4; ++j)                            \
        rsum[j] += __shfl_xor(rsum[j], o2, 64);                                \
    _Pragma("unroll") for (int j = 0; j < 4; ++j)                              \
      l_run[j] = l_run[j] * alpha[j] + rsum[j];                                \
    _Pragma("unroll") for (int nn = 0; nn < 8; ++nn)                           \
      _Pragma("unroll") for (int j = 0; j < 4; ++j) o[nn][j] *= alpha[j];      \
    _Pragma("unroll") for (int n = 0; n < 4; ++n)                              \
      _Pragma("unroll") for (int j = 0; j < 4; ++j) {                          \
        int pr = cg * 4 + j;                                                   \
        pw[pr * 64 + ((n * 16 + col) ^ ((pr & 7) << 3))] = f2bf(pv[n][j]);     \
      }                                                                        \
    asm volatile("s_waitcnt lgkmcnt(0)" ::: "memory");                         \
    __builtin_amdgcn_sched_barrier(0);                                         \
    _Pragma("unroll") for (int kk = 0; kk < 2; ++kk) {                         \
      bf16x8 pf = *(const bf16x8*)&pw[row * 64 + ((kk * 32 + kg) ^ kswz)];     \
      _Pragma("unroll") for (int nn = 0; nn < 8; ++nn) {                       \
        bf16x8 vf = *(const bf16x8*)&lds[16384 + buf * 8192 +                  \
                                         (nn * 16 + row) * 64 +                \
                                         ((kk * 32 + kg) ^ kswz)];             \
        o[nn] = __builtin_amdgcn_mfma_f32_16x16x32_bf16(pf, vf, o[nn], 0, 0, 0); \
      } }                                                                      \
    __builtin_amdgcn_s_barrier();                                              \
  } while (0)

__global__ __launch_bounds__(256) void attn_k(
    const unsigned short* __restrict__ Qr, const unsigned short* __restrict__ Kr,
    const unsigned short* __restrict__ Vt, const float* __restrict__ alibi,
    unsigned short* __restrict__ Ao, int S) {
  __shared__ unsigned short lds[36864];   // 72 KiB
  const int t = threadIdx.x, wave = t >> 6, lane = t & 63;
  const int h = blockIdx.y, nq = gridDim.x, bx = blockIdx.x;
  const int qt = (bx & 1) ? (nq - 1 - (bx >> 1)) : (bx >> 1);  // balance pairs
  const int q0 = qt * 64;
  const int sr = t >> 4, scw = ((t & 15) ^ ((t >> 4) & 7)) * 8;
  const int vr = t >> 3, vcw = ((t & 7) ^ ((t >> 3) & 7)) * 8;
  const unsigned short* Kb = Kr + (size_t)h * S * 128;
  const unsigned short* Vb = Vt + (size_t)h * 128 * S;
  const int row = lane & 15, kg = (lane >> 4) * 8, cg = lane >> 4, col = lane & 15;
  const int kswz = (lane & 7) << 3;
  bf16x8 qf[4];
  const unsigned short* Qrow = Qr + ((size_t)h * S + q0 + wave * 16 + row) * 128;
#pragma unroll
  for (int ks = 0; ks < 4; ++ks) qf[ks] = *(const bf16x8*)&Qrow[ks * 32 + kg];
  f32x4 o[8] = {};
  float m_run[4] = {-1e30f, -1e30f, -1e30f, -1e30f};
  float l_run[4] = {};
  unsigned short* pw = &lds[32768 + wave * 1024];
  const float scale = 0.08838834764831843f;
  const int ktiles = qt + 1;
  const float* albase = alibi + (size_t)h * S * S +
                        ((size_t)q0 + wave * 16 + cg * 4) * S + col;
  float alA[16], alB[16];
  STGKV(0, 0);
#pragma unroll
  for (int q8 = 0; q8 < 16; ++q8)
    alA[q8] = albase[(size_t)(q8 & 3) * S + (q8 >> 2) * 16];
  for (int kt = 0; kt < ktiles; kt += 2) {
    ATTN_TILE(alA, alB, kt);
    if (kt + 1 < ktiles) ATTN_TILE(alB, alA, kt + 1);
  }
#pragma unroll
  for (int nn = 0; nn < 8; ++nn)
#pragma unroll
    for (int j = 0; j < 4; ++j) {
      int q_abs = q0 + wave * 16 + cg * 4 + j;
      Ao[(size_t)q_abs * 2048 + h * 128 + nn * 16 + col] = f2bf(o[nn][j] / l_run[j]);
    }
}

// ---------- split-K reduce + residual: out = resid + sum_s part[s] ----------
__global__ __launch_bounds__(256) void reduce4_k(const float* __restrict__ part,
    const float* __restrict__ resid, float* __restrict__ out, int n4, size_t mn) {
  int i = blockIdx.x * 256 + threadIdx.x;
  if (i >= n4) return;
  const float4* p = (const float4*)part;
  size_t q = mn >> 2;
  float4 a = ((const float4*)resid)[i];
  float4 s0 = p[i], s1 = p[i + q], s2 = p[i + 2 * q], s3 = p[i + 3 * q];
  float4 r;
  r.x = a.x + s0.x + s1.x + s2.x + s3.x;
  r.y = a.y + s0.y + s1.y + s2.y + s3.y;
  r.z = a.z + s0.z + s1.z + s2.z + s3.z;
  r.w = a.w + s0.w + s1.w + s2.w + s3.w;
  ((float4*)out)[i] = r;
}

// ---------- host ----------
extern "C" void kernel_launch(void* const* d_in, const int* in_sizes, int n_in,
                              void* d_out, int out_size, void* d_ws, size_t ws_size,
                              hipStream_t stream) {
  const int S = 2048, H = 2048, NH = 16, DH = 128, FF = 8192;
  const float* x     = (const float*)d_in[0];
  const float* alibi = (const float*)d_in[2];
  const float* freqs = (const float*)d_in[3];
  const float* wq    = (const float*)d_in[4];
  const float* wk    = (const float*)d_in[5];
  const float* wv    = (const float*)d_in[6];
  const float* wo    = (const float*)d_in[7];
  const float* w1    = (const float*)d_in[8];
  const float* w2    = (const float*)d_in[9];
  const float* w3    = (const float*)d_in[10];
  const float* anw   = (const float*)d_in[11];
  const float* fnw   = (const float*)d_in[12];
  float* out = (float*)d_out;

  char* ws = (char*)d_ws;
  size_t off = 0;
  auto alloc = [&](size_t n) { char* p = ws + off; off += (n + 255) & ~(size_t)255; return p; };
  unsigned short* qkvT = (unsigned short*)alloc((size_t)3 * H * H * 2);
  unsigned short* woT  = (unsigned short*)alloc((size_t)H * H * 2);
  unsigned short* w13T = (unsigned short*)alloc((size_t)2 * FF * H * 2);
  unsigned short* w2T  = (unsigned short*)alloc((size_t)H * FF * 2);
  float*          x2   = (float*)alloc((size_t)S * H * 4);
  unsigned short* nx2  = (unsigned short*)alloc((size_t)S * H * 2);
  unsigned short* gbuf = (unsigned short*)alloc((size_t)S * FF * 2);
  unsigned short* nx   = (unsigned short*)alloc((size_t)S * H * 2);
  unsigned short* qkvb = (unsigned short*)alloc((size_t)S * 3 * H * 2);
  unsigned short* Qr   = (unsigned short*)alloc((size_t)NH * S * DH * 2);
  unsigned short* Kr   = (unsigned short*)alloc((size_t)NH * S * DH * 2);
  unsigned short* Vt   = (unsigned short*)alloc((size_t)NH * DH * S * 2);
  unsigned short* attno= (unsigned short*)alloc((size_t)S * H * 2);
  float* part4 = (float*)alloc((size_t)4 * S * H * 4);   // split-K partials

  wtrans4_k<<<dim3(32, 32, 4), 256, 0, stream>>>(
      wq, wk, wv, wo,
      qkvT, qkvT + (size_t)H * H, qkvT + (size_t)2 * H * H, woT, H, H);
  wtrans13_k<<<dim3(128, 32, 2), 256, 0, stream>>>(w1, w3, w13T, H, FF);
  wtrans64_k<<<dim3(32, 128), 256, 0, stream>>>(w2, w2T, FF, H, -1);

  rmsnorm_k<<<S, 256, 0, stream>>>(x, anw, nx, H);
  gemm256_k<0><<<dim3(192, 1), 512, 0, stream>>>(nx, H, qkvT, H, qkvb, nullptr, S, 3 * H, H);
  ropevt_k<<<12288, 256, 0, stream>>>(qkvb, freqs, Qr, Kr, Vt, S);
  attn_k<<<dim3(S / 64, NH), 256, 0, stream>>>(Qr, Kr, Vt, alibi, attno, S);
  // wo GEMM: split-K x4 on the 256^2 kernel (256 blocks), f32 partials
  gemm256_k<1><<<dim3(64, 4), 512, 0, stream>>>(attno, H, woT, H, nullptr, part4, S, H, 512);
  // fused: x2 = x + sum(partials); nx2 = rmsnorm(x2, fnw)
  reduce4rms_k<<<S, 256, 0, stream>>>(part4, x, fnw, x2, nx2, H, (size_t)S * H);
  gemm256_k<2><<<dim3(512, 1), 512, 0, stream>>>(nx2, H, w13T, H, gbuf, nullptr, S, 2 * FF, H);
  gemm256_k<1><<<dim3(64, 4), 512, 0, stream>>>(gbuf, FF, w2T, FF, nullptr, part4, S, H, FF / 4);
  reduce4_k<<<4096, 256, 0, stream>>>(part4, x2, out, S * H / 4, (size_t)S * H);
}